// Round 3
// baseline (254.909 us; speedup 1.0000x reference)
//
#include <hip/hip_runtime.h>
#include <hip/hip_bf16.h>
#include <math.h>

// Problem constants (from reference)
#define BATCH 2
#define NCAM 6
#define BN_TOT (BATCH * NCAM)   // 12
#define DBINS 112
#define HH 16
#define WW 44
#define CCH 80
#define VXD 128
#define VYD 128
#define HWD (HH * WW)           // 704
#define NCELL (VXD * VYD)       // 16384
#define NCELL_TOT (BATCH * NCELL)              // 32768
#define NPTS (BN_TOT * DBINS * HWD)            // 946176
#define PTS_PER_COL DBINS

// ---------------- workspace layout (bytes) ----------------
#define WS_PROB_OFF      0u
#define WS_PROB_BYTES    (NPTS * 4u)                       // 3,784,704  (bn,hw,d)
#define WS_CTXT_OFF      (WS_PROB_OFF + WS_PROB_BYTES)
#define WS_CTXT_BYTES    (BN_TOT * HWD * CCH * 4u)         // 2,703,360  (bn,hw,c)
#define WS_CELL_OFF      (WS_CTXT_OFF + WS_CTXT_BYTES)
#define WS_CELL_BYTES    (NPTS * 4u)                       // cellid per point
#define WS_PLIST_OFF     (WS_CELL_OFF + WS_CELL_BYTES)
#define WS_PLIST_BYTES   (NPTS * 4u)
#define WS_STARTS_OFF    (WS_PLIST_OFF + WS_PLIST_BYTES)
#define WS_STARTS_BYTES  ((NCELL_TOT + 4) * 4u)
#define WS_CURSOR_OFF    (WS_STARTS_OFF + WS_STARTS_BYTES)
#define WS_CURSOR_BYTES  (NCELL_TOT * 4u)
#define WS_ACCUM_OFF     ((WS_CURSOR_OFF + WS_CURSOR_BYTES + 15u) & ~15u)
#define WS_ACCUM_BYTES   (NCELL_TOT * CCH * 4u)            // 10,485,760 (b,cell,c)
#define WS_NEED          (WS_ACCUM_OFF + WS_ACCUM_BYTES)   // ~24.8 MB

// ============================================================
// Kernel A: per (bn,hw) column — softmax over D, transpose ctx,
// compute per-point cell ids, histogram into cursor[].
// ============================================================
__global__ __launch_bounds__(256) void prep_kernel(
    const float* __restrict__ depth_logits,  // (BN, D, H, W)
    const float* __restrict__ context,       // (BN, C, H, W)
    const int*   __restrict__ geom,          // (B, N, D, H, W, 3)
    float* __restrict__ prob,                // (BN, HW, D)
    float* __restrict__ ctxT,                // (BN, HW, C)
    int*   __restrict__ cellid,              // per point q
    int*   __restrict__ cursor) {            // histogram (zeroed)
  __shared__ float sred[256];

  const int blk = blockIdx.x;              // 0 .. BN*HW-1
  const int bn  = blk / HWD;
  const int hw  = blk - bn * HWD;
  const int b   = bn / NCAM;
  const int t   = threadIdx.x;

  // ---- softmax over depth bins ----
  float v = -INFINITY;
  if (t < DBINS) {
    v = depth_logits[(size_t)bn * DBINS * HWD + (size_t)t * HWD + hw];
  }
  sred[t] = v;
  __syncthreads();
  for (int s = 128; s > 0; s >>= 1) {
    if (t < s) sred[t] = fmaxf(sred[t], sred[t + s]);
    __syncthreads();
  }
  const float m = sred[0];
  __syncthreads();

  float e = 0.0f;
  if (t < DBINS) e = __expf(v - m);
  sred[t] = e;
  __syncthreads();
  for (int s = 128; s > 0; s >>= 1) {
    if (t < s) sred[t] += sred[t + s];
    __syncthreads();
  }
  const float inv_sum = 1.0f / sred[0];

  const int colbase = bn * HWD + hw;       // (bn,hw) flat

  if (t < DBINS) {
    prob[(size_t)colbase * DBINS + t] = e * inv_sum;   // contiguous in t
  }

  // ---- context transpose: (bn,c,hw) -> (bn,hw,c) ----
  if (t < CCH) {
    ctxT[(size_t)colbase * CCH + t] =
        context[((size_t)bn * CCH + t) * HWD + hw];
  }

  // ---- per-point voxel cell + histogram ----
  if (t < DBINS) {
    const size_t gbase = (((size_t)bn * DBINS + t) * HWD + hw) * 3;
    const int x = geom[gbase + 0];
    const int y = geom[gbase + 1];
    const int z = geom[gbase + 2];
    int cg = -1;
    if (x >= 0 && x < VXD && y >= 0 && y < VYD && z >= 0 && z < 128) {
      cg = (b << 14) + y * VXD + x;        // global cell id
      atomicAdd(&cursor[cg], 1);
    }
    cellid[(size_t)colbase * DBINS + t] = cg;
  }
}

// ============================================================
// Kernel B: single-block exclusive scan of cursor[] (counts) ->
// starts[] (NCELL_TOT+1 entries) and cursor[] reset to starts.
// ============================================================
__global__ __launch_bounds__(1024) void scan_kernel(
    int* __restrict__ starts, int* __restrict__ cursor) {
  __shared__ int sdata[1024];
  const int t = threadIdx.x;
  const int base = t * 32;                 // 1024*32 = 32768

  int cnt[32];
  int lsum = 0;
#pragma unroll
  for (int j = 0; j < 32; ++j) {
    cnt[j] = cursor[base + j];
    lsum += cnt[j];
  }
  sdata[t] = lsum;
  __syncthreads();
  for (int s = 1; s < 1024; s <<= 1) {
    int v = (t >= s) ? sdata[t - s] : 0;
    __syncthreads();
    sdata[t] += v;
    __syncthreads();
  }
  int run = sdata[t] - lsum;               // exclusive prefix of partials
#pragma unroll
  for (int j = 0; j < 32; ++j) {
    starts[base + j] = run;
    cursor[base + j] = run;
    run += cnt[j];
  }
  if (t == 1023) starts[NCELL_TOT] = run;  // total valid points
}

// ============================================================
// Kernel C: fill per-cell point lists.
// ============================================================
__global__ __launch_bounds__(256) void fill_kernel(
    const int* __restrict__ cellid, int* __restrict__ cursor,
    int* __restrict__ plist) {
  const int q = blockIdx.x * 256 + threadIdx.x;   // exact: 3696*256 = NPTS
  const int cg = cellid[q];
  if (cg >= 0) {
    const int pos = atomicAdd(&cursor[cg], 1);
    plist[pos] = q;
  }
}

// ============================================================
// Kernel D: gather — one wave per global cell; accumulate 80
// channels in registers; coalesced write to accum (b,cell,c).
// Empty cells write zeros (no memset of accum needed).
// ============================================================
__global__ __launch_bounds__(256) void gather_kernel(
    const int* __restrict__ starts, const int* __restrict__ plist,
    const float* __restrict__ prob, const float* __restrict__ ctxT,
    float* __restrict__ accum) {
  const int wid = threadIdx.x >> 6;
  const int lane = threadIdx.x & 63;
  const int cg = blockIdx.x * 4 + wid;     // global cell id, 0..32767

  const int s0 = starts[cg];
  const int s1 = starts[cg + 1];

  float a0 = 0.0f, a1 = 0.0f;
  for (int i = s0; i < s1; ++i) {
    const int q = plist[i];                // wave-uniform
    const float pr = prob[q];              // broadcast
    const float* cb = ctxT + (size_t)(q / DBINS) * CCH;
    a0 = fmaf(pr, cb[lane], a0);
    if (lane < CCH - 64) a1 = fmaf(pr, cb[64 + lane], a1);
  }
  float* dst = accum + (size_t)cg * CCH;
  dst[lane] = a0;
  if (lane < CCH - 64) dst[64 + lane] = a1;
}

// ============================================================
// Kernel E: accum (b,cell,c) -> out (b,c,cell). LDS tile padded
// to stride 81 (stride-80 was a 32-way bank conflict).
// ============================================================
__global__ __launch_bounds__(256) void transpose_kernel(
    const float* __restrict__ ws, float* __restrict__ out) {
  __shared__ float tile[64 * (CCH + 1)];
  const int blk = blockIdx.x;          // 0 .. B*256-1
  const int b = blk >> 8;
  const int cell0 = (blk & 255) * 64;

  const float* src = ws + (((size_t)b << 14) + cell0) * CCH;
  for (int p = threadIdx.x; p < 64 * CCH; p += 256) {
    const int i = p / CCH;
    const int c = p - i * CCH;
    tile[i * (CCH + 1) + c] = src[p];
  }
  __syncthreads();

  float* dst = out + (((size_t)b * CCH) << 14) + cell0;
  for (int p = threadIdx.x; p < 64 * CCH; p += 256) {
    const int c = p >> 6;
    const int i = p & 63;
    dst[(((size_t)c) << 14) + i] = tile[i * (CCH + 1) + c];
  }
}

// ============================================================
// Fallback: direct scatter-atomic kernel (if ws too small).
// ============================================================
template <int DIRECT>
__global__ __launch_bounds__(256) void lift_scatter_kernel(
    const float* __restrict__ depth_logits, const float* __restrict__ context,
    const int* __restrict__ geom, float* __restrict__ accum) {
  __shared__ float sred[256];
  __shared__ float sprob[DBINS];
  __shared__ float sctx[CCH];
  __shared__ int   scell[DBINS];

  const int blk = blockIdx.x;
  const int bn  = blk / HWD;
  const int hw  = blk - bn * HWD;
  const int b   = bn / NCAM;
  const int t   = threadIdx.x;

  float v = -INFINITY;
  if (t < DBINS) v = depth_logits[(size_t)bn * DBINS * HWD + (size_t)t * HWD + hw];
  sred[t] = v;
  __syncthreads();
  for (int s = 128; s > 0; s >>= 1) {
    if (t < s) sred[t] = fmaxf(sred[t], sred[t + s]);
    __syncthreads();
  }
  const float m = sred[0];
  __syncthreads();
  float e = 0.0f;
  if (t < DBINS) e = __expf(v - m);
  sred[t] = e;
  __syncthreads();
  for (int s = 128; s > 0; s >>= 1) {
    if (t < s) sred[t] += sred[t + s];
    __syncthreads();
  }
  if (t < DBINS) sprob[t] = e / sred[0];
  if (t < CCH) sctx[t] = context[((size_t)bn * CCH + t) * HWD + hw];
  if (t < DBINS) {
    const size_t gbase = (((size_t)bn * DBINS + t) * HWD + hw) * 3;
    const int x = geom[gbase + 0];
    const int y = geom[gbase + 1];
    const int z = geom[gbase + 2];
    scell[t] = (x >= 0 && x < VXD && y >= 0 && y < VYD && z >= 0 && z < 128)
                   ? y * VXD + x : -1;
  }
  __syncthreads();

  float* __restrict__ base = DIRECT ? (accum + (((size_t)b * CCH) << 14))
                                    : (accum + (((size_t)b << 14) * CCH));
  int d = t / CCH;
  int c = t - d * CCH;
#pragma unroll
  for (int k = 0; k < 35; ++k) {
    const int cell = scell[d];
    if (cell >= 0) {
      const float val = sprob[d] * sctx[c];
      if (DIRECT) unsafeAtomicAdd(base + (((size_t)c) << 14) + cell, val);
      else        unsafeAtomicAdd(base + (size_t)cell * CCH + c, val);
    }
    d += 3; c += 16;
    if (c >= CCH) { c -= CCH; d += 1; }
  }
}

extern "C" void kernel_launch(void* const* d_in, const int* in_sizes, int n_in,
                              void* d_out, int out_size, void* d_ws, size_t ws_size,
                              hipStream_t stream) {
  const float* depth_logits = (const float*)d_in[0];
  const float* context      = (const float*)d_in[1];
  const int*   geom         = (const int*)d_in[2];
  float* out = (float*)d_out;
  char* ws = (char*)d_ws;

  if (ws_size >= WS_NEED) {
    float* prob   = (float*)(ws + WS_PROB_OFF);
    float* ctxT   = (float*)(ws + WS_CTXT_OFF);
    int*   cellid = (int*)(ws + WS_CELL_OFF);
    int*   plist  = (int*)(ws + WS_PLIST_OFF);
    int*   starts = (int*)(ws + WS_STARTS_OFF);
    int*   cursor = (int*)(ws + WS_CURSOR_OFF);
    float* accum  = (float*)(ws + WS_ACCUM_OFF);

    hipMemsetAsync(cursor, 0, WS_CURSOR_BYTES, stream);
    prep_kernel<<<BN_TOT * HWD, 256, 0, stream>>>(
        depth_logits, context, geom, prob, ctxT, cellid, cursor);
    scan_kernel<<<1, 1024, 0, stream>>>(starts, cursor);
    fill_kernel<<<NPTS / 256, 256, 0, stream>>>(cellid, cursor, plist);
    gather_kernel<<<NCELL_TOT / 4, 256, 0, stream>>>(
        starts, plist, prob, ctxT, accum);
    transpose_kernel<<<BATCH * 256, 256, 0, stream>>>(accum, out);
  } else if (ws_size >= (size_t)NCELL_TOT * CCH * 4) {
    hipMemsetAsync(d_ws, 0, (size_t)NCELL_TOT * CCH * 4, stream);
    lift_scatter_kernel<0><<<BN_TOT * HWD, 256, 0, stream>>>(
        depth_logits, context, geom, (float*)d_ws);
    transpose_kernel<<<BATCH * 256, 256, 0, stream>>>((const float*)d_ws, out);
  } else {
    hipMemsetAsync(d_out, 0, (size_t)out_size * sizeof(float), stream);
    lift_scatter_kernel<1><<<BN_TOT * HWD, 256, 0, stream>>>(
        depth_logits, context, geom, out);
  }
}

// Round 4
// 228.099 us; speedup vs baseline: 1.1175x; 1.1175x over previous
//
#include <hip/hip_runtime.h>
#include <hip/hip_bf16.h>
#include <math.h>

// Problem constants (from reference)
#define BATCH 2
#define NCAM 6
#define BN_TOT (BATCH * NCAM)   // 12
#define DBINS 112
#define HH 16
#define WW 44
#define CCH 80
#define VXD 128
#define VYD 128
#define HWD (HH * WW)           // 704
#define NCELL (VXD * VYD)       // 16384
#define NCELL_TOT (BATCH * NCELL)      // 32768
#define NCOLS (BN_TOT * HWD)           // 8448 frustum columns
#define NPTS (NCOLS * DBINS)           // 946176 points
#define DCHUNK 28                      // 112 / 4

// ---------------- workspace layout (bytes), accum overlays pc+cursor ----------
#define WS_CTXT_OFF    0u
#define WS_CTXT_BYTES  ((unsigned)NCOLS * CCH * 4u)            // 2,703,360
#define WS_PLIST_OFF   (WS_CTXT_OFF + WS_CTXT_BYTES)
#define WS_PLIST_BYTES ((unsigned)NPTS * 8u)                   // 7,569,408
#define WS_STARTS_OFF  (WS_PLIST_OFF + WS_PLIST_BYTES)
#define WS_STARTS_BYTES 131328u                                // 32769 ints + pad
#define WS_PC_OFF      (WS_STARTS_OFF + WS_STARTS_BYTES)       // phase-1 only
#define WS_PC_BYTES    ((unsigned)NPTS * 8u)                   // 7,569,408
#define WS_CURSOR_OFF  (WS_PC_OFF + WS_PC_BYTES)               // phase-1 only
#define WS_CURSOR_BYTES ((unsigned)NCELL_TOT * 4u)             // 131,072
#define WS_ACCUM_OFF   WS_PC_OFF                               // overlays pc+cursor
#define WS_ACCUM_BYTES ((unsigned)NCELL_TOT * CCH * 4u)        // 10,485,760
#define WS_NEED        (WS_ACCUM_OFF + WS_ACCUM_BYTES)         // ~20.9 MB

// ============================================================
// Kernel A (prep): per 32-column tile; softmax over 112 bins
// (4 chunks of 28 kept in registers), geom -> cell id, 32K-bin
// histogram, writes pc[q] = {cell, prob_bits}, q = d*NCOLS+col.
// ============================================================
__global__ __launch_bounds__(128) void prep_kernel(
    const float* __restrict__ depth_logits,  // (BN, D, HW)
    const int*   __restrict__ geom,          // (BN, D, HW, 3)
    int2* __restrict__ pc,                   // (D, COL)
    int*  __restrict__ cursor) {             // histogram (pre-zeroed)
  __shared__ float sred[4][32];
  const int t = threadIdx.x;
  const int col_l = t & 31;
  const int chunk = t >> 5;
  const int blk = blockIdx.x;              // 12 * 22
  const int bn = blk / 22;
  const int tile = blk - bn * 22;
  const int hw = tile * 32 + col_l;
  const int b = bn / NCAM;
  const int col = bn * HWD + hw;

  const float* lp =
      depth_logits + ((size_t)bn * DBINS + chunk * DCHUNK) * HWD + hw;
  float v[DCHUNK];
  float m = -INFINITY;
#pragma unroll
  for (int j = 0; j < DCHUNK; ++j) {
    v[j] = lp[(size_t)j * HWD];
    m = fmaxf(m, v[j]);
  }
  sred[chunk][col_l] = m;
  __syncthreads();
  m = fmaxf(fmaxf(sred[0][col_l], sred[1][col_l]),
            fmaxf(sred[2][col_l], sred[3][col_l]));
  float lsum = 0.0f;
#pragma unroll
  for (int j = 0; j < DCHUNK; ++j) {
    v[j] = __expf(v[j] - m);
    lsum += v[j];
  }
  __syncthreads();
  sred[chunk][col_l] = lsum;
  __syncthreads();
  const float inv = 1.0f / (sred[0][col_l] + sred[1][col_l] +
                            sred[2][col_l] + sred[3][col_l]);

  const int* gp = geom + (((size_t)bn * DBINS + chunk * DCHUNK) * HWD + hw) * 3;
#pragma unroll 4
  for (int j = 0; j < DCHUNK; ++j) {
    const int x = gp[(size_t)j * HWD * 3 + 0];
    const int y = gp[(size_t)j * HWD * 3 + 1];
    const int z = gp[(size_t)j * HWD * 3 + 2];
    int cell = -1;
    if (((unsigned)x < (unsigned)VXD) & ((unsigned)y < (unsigned)VYD) &
        ((unsigned)z < 128u)) {
      cell = (b << 14) + (y << 7) + x;
      atomicAdd(&cursor[cell], 1);
    }
    pc[(size_t)(chunk * DCHUNK + j) * NCOLS + col] =
        make_int2(cell, __float_as_int(v[j] * inv));
  }
}

// ============================================================
// Kernel B (ctxT): context (BN,C,HW) -> ctxT (COL,C), LDS-tiled.
// ============================================================
__global__ __launch_bounds__(256) void ctxt_kernel(
    const float* __restrict__ context, float* __restrict__ ctxT) {
  __shared__ float tile[CCH][65];
  const int blk = blockIdx.x;              // 12 * 11
  const int bn = blk / 11;
  const int hw0 = (blk - bn * 11) * 64;
  const float* src = context + (size_t)bn * CCH * HWD + hw0;
  for (int p = threadIdx.x; p < CCH * 64; p += 256) {
    const int c = p >> 6;
    const int i = p & 63;
    tile[c][i] = src[(size_t)c * HWD + i];
  }
  __syncthreads();
  float* dst = ctxT + (size_t)(bn * HWD + hw0) * CCH;
  for (int p = threadIdx.x; p < CCH * 64; p += 256) {
    const int i = p / CCH;
    const int c = p - i * CCH;
    dst[p] = tile[c][i];
  }
}

// ============================================================
// Kernel C (scan): 1 block, shuffle-based exclusive scan of the
// 32768 histogram counts -> starts[]; cursor[] reset to starts.
// ============================================================
__global__ __launch_bounds__(1024) void scan_kernel(
    int* __restrict__ starts, int* __restrict__ cursor) {
  __shared__ int wsum[16];
  const int t = threadIdx.x;
  const int lane = t & 63;
  const int wid = t >> 6;
  int c[32];
  const int4* src = (const int4*)cursor + (size_t)t * 8;
  int lsum = 0;
#pragma unroll
  for (int j = 0; j < 8; ++j) {
    const int4 q = src[j];
    c[j * 4 + 0] = q.x; c[j * 4 + 1] = q.y;
    c[j * 4 + 2] = q.z; c[j * 4 + 3] = q.w;
    lsum += q.x + q.y + q.z + q.w;
  }
  int incl = lsum;
#pragma unroll
  for (int d = 1; d < 64; d <<= 1) {
    const int u = __shfl_up(incl, d, 64);
    if (lane >= d) incl += u;
  }
  if (lane == 63) wsum[wid] = incl;
  __syncthreads();
  if (t < 16) {
    const int v = wsum[t];
    int iv = v;
#pragma unroll
    for (int d = 1; d < 16; d <<= 1) {
      const int u = __shfl_up(iv, d, 16);
      if (t >= d) iv += u;
    }
    wsum[t] = iv - v;  // exclusive
  }
  __syncthreads();
  int run = wsum[wid] + incl - lsum;
  int4* ds = (int4*)starts + (size_t)t * 8;
  int4* dc = (int4*)cursor + (size_t)t * 8;
#pragma unroll
  for (int j = 0; j < 8; ++j) {
    int4 o;
    o.x = run; run += c[j * 4 + 0];
    o.y = run; run += c[j * 4 + 1];
    o.z = run; run += c[j * 4 + 2];
    o.w = run; run += c[j * 4 + 3];
    ds[j] = o;
    dc[j] = o;
  }
  if (t == 1023) starts[NCELL_TOT] = run;
}

// ============================================================
// Kernel D (fill): scatter payload {col, prob_bits} into the
// per-cell segments.
// ============================================================
__global__ __launch_bounds__(256) void fill_kernel(
    const int2* __restrict__ pc, int* __restrict__ cursor,
    int2* __restrict__ plist) {
  const int q = blockIdx.x * 256 + threadIdx.x;  // 3696*256 == NPTS
  const int2 p = pc[q];
  if (p.x >= 0) {
    const int pos = atomicAdd(&cursor[p.x], 1);
    const int d = q / NCOLS;
    const int col = q - d * NCOLS;
    plist[pos] = make_int2(col, p.y);
  }
}

// ============================================================
// Kernel E (gather): wave per cell. 64 payloads loaded per wave
// in one coalesced load, broadcast by shuffle; inner loop
// unrolled x4 for load-level parallelism. Registers hold the 80
// channels; one coalesced write; empty cells write zeros.
// ============================================================
__global__ __launch_bounds__(256) void gather_kernel(
    const int* __restrict__ starts, const int2* __restrict__ plist,
    const float* __restrict__ ctxT, float* __restrict__ accum) {
  const int wid = threadIdx.x >> 6;
  const int lane = threadIdx.x & 63;
  const int cg = blockIdx.x * 4 + wid;
  const int s0 = starts[cg];
  const int s1 = starts[cg + 1];
  float a0 = 0.0f, a1 = 0.0f;
  for (int base = s0; base < s1; base += 64) {
    const int nb = min(64, s1 - base);
    int2 pay = make_int2(0, 0);
    if (lane < nb) pay = plist[base + lane];
    int j = 0;
    for (; j + 4 <= nb; j += 4) {
      const int col0 = __shfl(pay.x, j);
      const int col1 = __shfl(pay.x, j + 1);
      const int col2 = __shfl(pay.x, j + 2);
      const int col3 = __shfl(pay.x, j + 3);
      const float p0 = __int_as_float(__shfl(pay.y, j));
      const float p1 = __int_as_float(__shfl(pay.y, j + 1));
      const float p2 = __int_as_float(__shfl(pay.y, j + 2));
      const float p3 = __int_as_float(__shfl(pay.y, j + 3));
      const float* c0 = ctxT + (size_t)col0 * CCH;
      const float* c1 = ctxT + (size_t)col1 * CCH;
      const float* c2 = ctxT + (size_t)col2 * CCH;
      const float* c3 = ctxT + (size_t)col3 * CCH;
      const float f0 = c0[lane];
      const float f1 = c1[lane];
      const float f2 = c2[lane];
      const float f3 = c3[lane];
      a0 = fmaf(p0, f0, a0);
      a0 = fmaf(p1, f1, a0);
      a0 = fmaf(p2, f2, a0);
      a0 = fmaf(p3, f3, a0);
      if (lane < CCH - 64) {
        a1 = fmaf(p0, c0[64 + lane], a1);
        a1 = fmaf(p1, c1[64 + lane], a1);
        a1 = fmaf(p2, c2[64 + lane], a1);
        a1 = fmaf(p3, c3[64 + lane], a1);
      }
    }
    for (; j < nb; ++j) {
      const int col = __shfl(pay.x, j);
      const float pr = __int_as_float(__shfl(pay.y, j));
      const float* cb = ctxT + (size_t)col * CCH;
      a0 = fmaf(pr, cb[lane], a0);
      if (lane < CCH - 64) a1 = fmaf(pr, cb[64 + lane], a1);
    }
  }
  float* dst = accum + (size_t)cg * CCH;
  dst[lane] = a0;
  if (lane < CCH - 64) dst[64 + lane] = a1;
}

// ============================================================
// Kernel F (transpose): accum (b,cell,c) -> out (b,c,cell).
// ============================================================
__global__ __launch_bounds__(256) void transpose_kernel(
    const float* __restrict__ ws, float* __restrict__ out) {
  __shared__ float tile[64 * (CCH + 1)];
  const int blk = blockIdx.x;          // 0 .. B*256-1
  const int b = blk >> 8;
  const int cell0 = (blk & 255) * 64;

  const float* src = ws + (((size_t)b << 14) + cell0) * CCH;
  for (int p = threadIdx.x; p < 64 * CCH; p += 256) {
    const int i = p / CCH;
    const int c = p - i * CCH;
    tile[i * (CCH + 1) + c] = src[p];
  }
  __syncthreads();

  float* dst = out + (((size_t)b * CCH) << 14) + cell0;
  for (int p = threadIdx.x; p < 64 * CCH; p += 256) {
    const int c = p >> 6;
    const int i = p & 63;
    dst[(((size_t)c) << 14) + i] = tile[i * (CCH + 1) + c];
  }
}

// ============================================================
// Fallback: direct scatter-atomic (if ws too small).
// ============================================================
__global__ __launch_bounds__(256) void lift_scatter_kernel(
    const float* __restrict__ depth_logits, const float* __restrict__ context,
    const int* __restrict__ geom, float* __restrict__ accum) {
  __shared__ float sred[256];
  __shared__ float sprob[DBINS];
  __shared__ float sctx[CCH];
  __shared__ int   scell[DBINS];

  const int blk = blockIdx.x;
  const int bn  = blk / HWD;
  const int hw  = blk - bn * HWD;
  const int b   = bn / NCAM;
  const int t   = threadIdx.x;

  float v = -INFINITY;
  if (t < DBINS) v = depth_logits[(size_t)bn * DBINS * HWD + (size_t)t * HWD + hw];
  sred[t] = v;
  __syncthreads();
  for (int s = 128; s > 0; s >>= 1) {
    if (t < s) sred[t] = fmaxf(sred[t], sred[t + s]);
    __syncthreads();
  }
  const float m = sred[0];
  __syncthreads();
  float e = 0.0f;
  if (t < DBINS) e = __expf(v - m);
  sred[t] = e;
  __syncthreads();
  for (int s = 128; s > 0; s >>= 1) {
    if (t < s) sred[t] += sred[t + s];
    __syncthreads();
  }
  if (t < DBINS) sprob[t] = e / sred[0];
  if (t < CCH) sctx[t] = context[((size_t)bn * CCH + t) * HWD + hw];
  if (t < DBINS) {
    const size_t gbase = (((size_t)bn * DBINS + t) * HWD + hw) * 3;
    const int x = geom[gbase + 0];
    const int y = geom[gbase + 1];
    const int z = geom[gbase + 2];
    scell[t] = (x >= 0 && x < VXD && y >= 0 && y < VYD && z >= 0 && z < 128)
                   ? y * VXD + x : -1;
  }
  __syncthreads();

  float* __restrict__ base = accum + (((size_t)b * CCH) << 14);
  int d = t / CCH;
  int c = t - d * CCH;
#pragma unroll
  for (int k = 0; k < 35; ++k) {
    const int cell = scell[d];
    if (cell >= 0) {
      unsafeAtomicAdd(base + (((size_t)c) << 14) + cell, sprob[d] * sctx[c]);
    }
    d += 3; c += 16;
    if (c >= CCH) { c -= CCH; d += 1; }
  }
}

extern "C" void kernel_launch(void* const* d_in, const int* in_sizes, int n_in,
                              void* d_out, int out_size, void* d_ws, size_t ws_size,
                              hipStream_t stream) {
  const float* depth_logits = (const float*)d_in[0];
  const float* context      = (const float*)d_in[1];
  const int*   geom         = (const int*)d_in[2];
  float* out = (float*)d_out;
  char* ws = (char*)d_ws;

  if (ws_size >= WS_NEED) {
    float* ctxT   = (float*)(ws + WS_CTXT_OFF);
    int2*  plist  = (int2*)(ws + WS_PLIST_OFF);
    int*   starts = (int*)(ws + WS_STARTS_OFF);
    int2*  pc     = (int2*)(ws + WS_PC_OFF);
    int*   cursor = (int*)(ws + WS_CURSOR_OFF);
    float* accum  = (float*)(ws + WS_ACCUM_OFF);  // overlays pc+cursor

    hipMemsetAsync(cursor, 0, WS_CURSOR_BYTES, stream);
    prep_kernel<<<BN_TOT * 22, 128, 0, stream>>>(depth_logits, geom, pc, cursor);
    ctxt_kernel<<<BN_TOT * 11, 256, 0, stream>>>(context, ctxT);
    scan_kernel<<<1, 1024, 0, stream>>>(starts, cursor);
    fill_kernel<<<NPTS / 256, 256, 0, stream>>>(pc, cursor, plist);
    gather_kernel<<<NCELL_TOT / 4, 256, 0, stream>>>(starts, plist, ctxT, accum);
    transpose_kernel<<<BATCH * 256, 256, 0, stream>>>(accum, out);
  } else {
    hipMemsetAsync(d_out, 0, (size_t)out_size * sizeof(float), stream);
    lift_scatter_kernel<<<BN_TOT * HWD, 256, 0, stream>>>(
        depth_logits, context, geom, out);
  }
}

// Round 7
// 194.312 us; speedup vs baseline: 1.3119x; 1.1739x over previous
//
#include <hip/hip_runtime.h>
#include <hip/hip_bf16.h>
#include <math.h>

// Problem constants (from reference)
#define BATCH 2
#define NCAM 6
#define BN_TOT (BATCH * NCAM)   // 12
#define DBINS 112
#define HH 16
#define WW 44
#define CCH 80
#define VXD 128
#define VYD 128
#define HWD (HH * WW)           // 704
#define NCELL (VXD * VYD)       // 16384
#define NCELL_TOT (BATCH * NCELL)      // 32768
#define NCOLS (BN_TOT * HWD)           // 8448 frustum columns
#define NPTS (NCOLS * DBINS)           // 946176 points
#define DCHUNK 28                      // 112 / 4

#define NBLK_PREP 264                  // 12 bn * 22 col-tiles of 32
#define PREP_PTS 3584                  // 32 cols * 112 bins
#define NBUCKET 512                    // bucket = cell >> 6 = (b<<8)|(y<<1)|(x>>6)
#define FLATN (NBUCKET * NBLK_PREP)    // 135168 = 1024 * 132
#define SOLVE_CAP 2560                 // >> max multinomial(~1848) bucket size

// ---------------- workspace layout (bytes), all 16B-aligned ----------------
#define WS_CTXT_OFF    0u
#define WS_CTXT_BYTES  ((unsigned)NCOLS * CCH * 4u)            // 2,703,360
#define WS_PC_OFF      (WS_CTXT_OFF + WS_CTXT_BYTES)
#define WS_PC_BYTES    ((unsigned)NPTS * 8u)                   // 7,569,408
#define WS_PLIST_OFF   (WS_PC_OFF + WS_PC_BYTES)
#define WS_PLIST_BYTES ((unsigned)NPTS * 8u)                   // 7,569,408
#define WS_CNT_OFF     (WS_PLIST_OFF + WS_PLIST_BYTES)
#define WS_CNT_BYTES   ((unsigned)FLATN * 4u)                  // 540,672
#define WS_BST_OFF     (WS_CNT_OFF + WS_CNT_BYTES)
#define WS_BST_BYTES   2064u                                   // 513 ints + pad
#define WS_NEED        (WS_BST_OFF + WS_BST_BYTES)             // ~18.4 MB

// ============================================================
// K1 (prep): per 32-column tile; softmax over 112 bins (4x28 in
// regs), geom -> cell id, write pc[q]={cell,prob}, LDS 512-bucket
// histogram -> counts[bucket][blk]. NO global atomics.
// ============================================================
__global__ __launch_bounds__(128) void prep_kernel(
    const float* __restrict__ depth_logits,  // (BN, D, HW)
    const int*   __restrict__ geom,          // (BN, D, HW, 3)
    int2* __restrict__ pc,                   // (D, COL) = {cell, prob_bits}
    int*  __restrict__ counts) {             // [512][264]
  __shared__ float sred[4][32];
  __shared__ int shist[NBUCKET];
  const int t = threadIdx.x;
  for (int i = t; i < NBUCKET; i += 128) shist[i] = 0;

  const int col_l = t & 31;
  const int chunk = t >> 5;
  const int blk = blockIdx.x;              // 12 * 22
  const int bn = blk / 22;
  const int tile22 = blk - bn * 22;
  const int hw = tile22 * 32 + col_l;
  const int b = bn / NCAM;
  const int col = bn * HWD + hw;

  const float* lp =
      depth_logits + ((size_t)bn * DBINS + chunk * DCHUNK) * HWD + hw;
  float v[DCHUNK];
  float m = -INFINITY;
#pragma unroll
  for (int j = 0; j < DCHUNK; ++j) {
    v[j] = lp[(size_t)j * HWD];
    m = fmaxf(m, v[j]);
  }
  sred[chunk][col_l] = m;
  __syncthreads();
  m = fmaxf(fmaxf(sred[0][col_l], sred[1][col_l]),
            fmaxf(sred[2][col_l], sred[3][col_l]));
  float lsum = 0.0f;
#pragma unroll
  for (int j = 0; j < DCHUNK; ++j) {
    v[j] = __expf(v[j] - m);
    lsum += v[j];
  }
  __syncthreads();
  sred[chunk][col_l] = lsum;
  __syncthreads();
  const float inv = 1.0f / (sred[0][col_l] + sred[1][col_l] +
                            sred[2][col_l] + sred[3][col_l]);

  const int* gp = geom + (((size_t)bn * DBINS + chunk * DCHUNK) * HWD + hw) * 3;
#pragma unroll 4
  for (int j = 0; j < DCHUNK; ++j) {
    const int x = gp[(size_t)j * HWD * 3 + 0];
    const int y = gp[(size_t)j * HWD * 3 + 1];
    const int z = gp[(size_t)j * HWD * 3 + 2];
    int cell = -1;
    if (((unsigned)x < (unsigned)VXD) & ((unsigned)y < (unsigned)VYD) &
        ((unsigned)z < 128u)) {
      cell = (b << 14) + (y << 7) + x;
      atomicAdd(&shist[cell >> 6], 1);   // LDS
    }
    pc[(size_t)(chunk * DCHUNK + j) * NCOLS + col] =
        make_int2(cell, __float_as_int(v[j] * inv));
  }
  __syncthreads();
  for (int i = t; i < NBUCKET; i += 128) counts[i * NBLK_PREP + blk] = shist[i];
}

// ============================================================
// K2 (ctxT): context (BN,C,HW) -> ctxT (COL,C), LDS-tiled.
// ============================================================
__global__ __launch_bounds__(256) void ctxt_kernel(
    const float* __restrict__ context, float* __restrict__ ctxT) {
  __shared__ float tile[CCH][65];
  const int blk = blockIdx.x;              // 12 * 11
  const int bn = blk / 11;
  const int hw0 = (blk - bn * 11) * 64;
  const float* src = context + (size_t)bn * CCH * HWD + hw0;
  for (int p = threadIdx.x; p < CCH * 64; p += 256) {
    const int c = p >> 6;
    const int i = p & 63;
    tile[c][i] = src[(size_t)c * HWD + i];
  }
  __syncthreads();
  float* dst = ctxT + (size_t)(bn * HWD + hw0) * CCH;
  for (int p = threadIdx.x; p < CCH * 64; p += 256) {
    const int i = p / CCH;
    const int c = p - i * CCH;
    dst[p] = tile[c][i];
  }
}

// ============================================================
// K3 (scan): 1 block, in-place exclusive scan of counts[512][264]
// (bucket-major flat) + bucketStart[513].
// ============================================================
__global__ __launch_bounds__(1024) void scan_kernel(
    int* __restrict__ counts, int* __restrict__ bucketStart) {
  __shared__ int wpart[16];
  const int t = threadIdx.x;
  const int lane = t & 63;
  const int wid = t >> 6;
  const int4* src = (const int4*)counts + (size_t)t * 33;  // 132 ints/thread
  int lsum = 0;
#pragma unroll
  for (int j = 0; j < 33; ++j) {
    const int4 q = src[j];
    lsum += q.x + q.y + q.z + q.w;
  }
  int incl = lsum;
#pragma unroll
  for (int d = 1; d < 64; d <<= 1) {
    const int u = __shfl_up(incl, d, 64);
    if (lane >= d) incl += u;
  }
  if (lane == 63) wpart[wid] = incl;
  __syncthreads();
  if (t < 16) {
    const int v = wpart[t];
    int iv = v;
#pragma unroll
    for (int d = 1; d < 16; d <<= 1) {
      const int u = __shfl_up(iv, d, 16);
      if (t >= d) iv += u;
    }
    wpart[t] = iv - v;  // exclusive
  }
  __syncthreads();
  int run = wpart[wid] + incl - lsum;     // exclusive prefix at t*132
  if ((t & 1) == 0) bucketStart[t >> 1] = run;   // t*132 % 264 == 0
  int4* dst = (int4*)counts + (size_t)t * 33;
#pragma unroll
  for (int j = 0; j < 33; ++j) {
    const int4 q = src[j];                // re-read (own chunk, no hazard)
    int4 o;
    o.x = run; run += q.x;
    o.y = run; run += q.y;
    o.z = run; run += q.z;
    o.w = run; run += q.w;
    dst[j] = o;
  }
  if (t == 1023) bucketStart[NBUCKET] = run;
}

// ============================================================
// K4 (partition): mirror prep's point grouping; in-LDS counting
// sort by bucket; flush contiguous runs at exact global offsets.
// Zero global atomics.
// ============================================================
__global__ __launch_bounds__(256) void partition_kernel(
    const int2* __restrict__ pc,
    const int*  __restrict__ offsets,    // [512][264] (scanned counts)
    int2* __restrict__ plist) {
  __shared__ int hist[NBUCKET], hoff[NBUCKET], hcur[NBUCKET], gdst[NBUCKET];
  __shared__ int2 stag[PREP_PTS];
  __shared__ int gaddr[PREP_PTS];
  __shared__ int wpart2[4];
  const int t = threadIdx.x;
  const int blk = blockIdx.x;            // 264, mirrors prep
  const int bn = blk / 22;
  const int tile22 = blk - bn * 22;
  const int colbase = bn * HWD + tile22 * 32;

  for (int i = t; i < NBUCKET; i += 256) hist[i] = 0;
  __syncthreads();

  int2 pay[14];
  int  bkt[14];
#pragma unroll
  for (int j = 0; j < 14; ++j) {
    const int p = t + j * 256;           // 0..3583
    const int d = p >> 5;
    const int col = colbase + (p & 31);
    const int2 pp = pc[(size_t)d * NCOLS + col];
    int bk = -1;
    if (pp.x >= 0) {
      bk = pp.x >> 6;
      atomicAdd(&hist[bk], 1);           // LDS
      pay[j] = make_int2(((pp.x & 63) << 14) | col, pp.y);
    }
    bkt[j] = bk;
  }
  __syncthreads();

  // scan 512 bins with 256 threads (2 bins each)
  const int lane = t & 63, wid = t >> 6;
  const int h0 = hist[2 * t], h1 = hist[2 * t + 1];
  const int s2 = h0 + h1;
  int incl = s2;
#pragma unroll
  for (int d = 1; d < 64; d <<= 1) {
    const int u = __shfl_up(incl, d, 64);
    if (lane >= d) incl += u;
  }
  if (lane == 63) wpart2[wid] = incl;
  __syncthreads();
  int wbase = 0;
  if (wid == 1) wbase = wpart2[0];
  else if (wid == 2) wbase = wpart2[0] + wpart2[1];
  else if (wid == 3) wbase = wpart2[0] + wpart2[1] + wpart2[2];
  const int ex = wbase + incl - s2;
  hoff[2 * t] = ex;
  hoff[2 * t + 1] = ex + h0;
  hcur[2 * t] = 0;
  hcur[2 * t + 1] = 0;
  gdst[2 * t]     = offsets[(2 * t) * NBLK_PREP + blk];
  gdst[2 * t + 1] = offsets[(2 * t + 1) * NBLK_PREP + blk];
  __syncthreads();

  // scatter into staged (bucket-sorted) order
#pragma unroll
  for (int j = 0; j < 14; ++j) {
    if (bkt[j] >= 0) {
      const int r = atomicAdd(&hcur[bkt[j]], 1);   // LDS
      const int pos = hoff[bkt[j]] + r;
      stag[pos] = pay[j];
      gaddr[pos] = gdst[bkt[j]] + r;
    }
  }
  __syncthreads();

  const int nval = hoff[NBUCKET - 1] + hist[NBUCKET - 1];
  for (int i = t; i < nval; i += 256) {
    plist[gaddr[i]] = stag[i];           // coalesced runs per bucket
  }
}

// ============================================================
// K5 (solve): block per bucket (b,y,x-half = 64 cells). Load
// payloads to LDS, counting-sort by cell, wave-per-cell register
// gather (x4 unrolled ctxT row loads), stage tile, write final
// (b,c,y,x) layout directly. Covers every output element.
// ============================================================
__global__ __launch_bounds__(256) void solve_kernel(
    const int*  __restrict__ bucketStart,
    const int2* __restrict__ plist,
    const float* __restrict__ ctxT,
    float* __restrict__ out) {
  __shared__ int2 spts[SOLVE_CAP];
  __shared__ float tile[64 * 81];
  __shared__ int hist[64], starts[65], cur[64];
  const int t = threadIdx.x;
  const int k = blockIdx.x;              // 512
  const int b = k >> 8;
  const int y = (k & 255) >> 1;
  const int x0 = (k & 1) << 6;
  const int bs = bucketStart[k];
  const int be = bucketStart[k + 1];
  const int n_all = be - bs;
  const int n = min(n_all, SOLVE_CAP);

  if (t < 64) hist[t] = 0;
  __syncthreads();

  int2 rp[10];                           // ceil(2560/256)
  int nper = 0;
#pragma unroll
  for (int j = 0; j < 10; ++j) {
    const int i = t + j * 256;
    if (i < n) {
      const int2 p = plist[bs + i];
      rp[j] = p;
      atomicAdd(&hist[(p.x >> 14) & 63], 1);   // LDS
      nper = j + 1;
    }
  }
  __syncthreads();

  const int lane = t & 63, wid = t >> 6;
  if (t < 64) {
    const int h = hist[t];
    int incl = h;
#pragma unroll
    for (int d = 1; d < 64; d <<= 1) {
      const int u = __shfl_up(incl, d, 64);
      if (t >= d) incl += u;
    }
    starts[t] = incl - h;
    cur[t] = incl - h;
    if (t == 63) starts[64] = incl;
  }
  __syncthreads();

#pragma unroll
  for (int j = 0; j < 10; ++j) {
    if (j < nper) {
      const int key = (rp[j].x >> 14) & 63;
      const int r = atomicAdd(&cur[key], 1);   // LDS
      spts[r] = rp[j];
    }
  }
  __syncthreads();

  // wave handles 16 cells
  for (int ci = 0; ci < 16; ++ci) {
    const int xl = wid * 16 + ci;
    const int s0 = starts[xl];
    const int s1 = starts[xl + 1];
    float a0 = 0.0f, a1 = 0.0f;
    int i = s0;
    for (; i + 4 <= s1; i += 4) {
      const int2 p0 = spts[i], p1 = spts[i + 1], p2 = spts[i + 2], p3 = spts[i + 3];
      const float* c0 = ctxT + (size_t)(p0.x & 0x3FFF) * CCH;
      const float* c1 = ctxT + (size_t)(p1.x & 0x3FFF) * CCH;
      const float* c2 = ctxT + (size_t)(p2.x & 0x3FFF) * CCH;
      const float* c3 = ctxT + (size_t)(p3.x & 0x3FFF) * CCH;
      const float q0 = __int_as_float(p0.y), q1 = __int_as_float(p1.y);
      const float q2 = __int_as_float(p2.y), q3 = __int_as_float(p3.y);
      const float f0 = c0[lane], f1 = c1[lane], f2 = c2[lane], f3 = c3[lane];
      a0 = fmaf(q0, f0, a0);
      a0 = fmaf(q1, f1, a0);
      a0 = fmaf(q2, f2, a0);
      a0 = fmaf(q3, f3, a0);
      if (lane < CCH - 64) {
        a1 = fmaf(q0, c0[64 + lane], a1);
        a1 = fmaf(q1, c1[64 + lane], a1);
        a1 = fmaf(q2, c2[64 + lane], a1);
        a1 = fmaf(q3, c3[64 + lane], a1);
      }
    }
    for (; i < s1; ++i) {
      const int2 p = spts[i];
      const float pr = __int_as_float(p.y);
      const float* cb = ctxT + (size_t)(p.x & 0x3FFF) * CCH;
      a0 = fmaf(pr, cb[lane], a0);
      if (lane < CCH - 64) a1 = fmaf(pr, cb[64 + lane], a1);
    }
    tile[xl * 81 + lane] = a0;
    if (lane < CCH - 64) tile[xl * 81 + 64 + lane] = a1;
  }

  // overflow tail (statistically never taken; kept for correctness)
  for (int i = SOLVE_CAP; i < n_all; ++i) {
    const int2 p = plist[bs + i];
    const int key = (p.x >> 14) & 63;
    if ((key >> 4) == wid) {
      const float pr = __int_as_float(p.y);
      const float* cb = ctxT + (size_t)(p.x & 0x3FFF) * CCH;
      tile[key * 81 + lane] += pr * cb[lane];
      if (lane < CCH - 64) tile[key * 81 + 64 + lane] += pr * cb[64 + lane];
    }
  }
  __syncthreads();

  // write out[b][c][y][x0..x0+63], coalesced 256B rows
  float* dst = out + (((size_t)(b * CCH)) << 14) + (y << 7) + x0;
  for (int p = t; p < CCH * 64; p += 256) {
    const int c = p >> 6;
    const int xl = p & 63;
    dst[((size_t)c << 14) + xl] = tile[xl * 81 + c];
  }
}

// ============================================================
// Fallback: direct scatter-atomic (if ws too small).
// ============================================================
__global__ __launch_bounds__(256) void lift_scatter_kernel(
    const float* __restrict__ depth_logits, const float* __restrict__ context,
    const int* __restrict__ geom, float* __restrict__ accum) {
  __shared__ float sred[256];
  __shared__ float sprob[DBINS];
  __shared__ float sctx[CCH];
  __shared__ int   scell[DBINS];

  const int blk = blockIdx.x;
  const int bn  = blk / HWD;
  const int hw  = blk - bn * HWD;
  const int b   = bn / NCAM;
  const int t   = threadIdx.x;

  float v = -INFINITY;
  if (t < DBINS) v = depth_logits[(size_t)bn * DBINS * HWD + (size_t)t * HWD + hw];
  sred[t] = v;
  __syncthreads();
  for (int s = 128; s > 0; s >>= 1) {
    if (t < s) sred[t] = fmaxf(sred[t], sred[t + s]);
    __syncthreads();
  }
  const float m = sred[0];
  __syncthreads();
  float e = 0.0f;
  if (t < DBINS) e = __expf(v - m);
  sred[t] = e;
  __syncthreads();
  for (int s = 128; s > 0; s >>= 1) {
    if (t < s) sred[t] += sred[t + s];
    __syncthreads();
  }
  if (t < DBINS) sprob[t] = e / sred[0];
  if (t < CCH) sctx[t] = context[((size_t)bn * CCH + t) * HWD + hw];
  if (t < DBINS) {
    const size_t gbase = (((size_t)bn * DBINS + t) * HWD + hw) * 3;
    const int x = geom[gbase + 0];
    const int y = geom[gbase + 1];
    const int z = geom[gbase + 2];
    scell[t] = (x >= 0 && x < VXD && y >= 0 && y < VYD && z >= 0 && z < 128)
                   ? y * VXD + x : -1;
  }
  __syncthreads();

  float* __restrict__ base = accum + (((size_t)b * CCH) << 14);
  int d = t / CCH;
  int c = t - d * CCH;
#pragma unroll
  for (int k = 0; k < 35; ++k) {
    const int cell = scell[d];
    if (cell >= 0) {
      unsafeAtomicAdd(base + (((size_t)c) << 14) + cell, sprob[d] * sctx[c]);
    }
    d += 3; c += 16;
    if (c >= CCH) { c -= CCH; d += 1; }
  }
}

extern "C" void kernel_launch(void* const* d_in, const int* in_sizes, int n_in,
                              void* d_out, int out_size, void* d_ws, size_t ws_size,
                              hipStream_t stream) {
  const float* depth_logits = (const float*)d_in[0];
  const float* context      = (const float*)d_in[1];
  const int*   geom         = (const int*)d_in[2];
  float* out = (float*)d_out;
  char* ws = (char*)d_ws;

  if (ws_size >= WS_NEED) {
    float* ctxT   = (float*)(ws + WS_CTXT_OFF);
    int2*  pc     = (int2*)(ws + WS_PC_OFF);
    int2*  plist  = (int2*)(ws + WS_PLIST_OFF);
    int*   counts = (int*)(ws + WS_CNT_OFF);
    int*   bstart = (int*)(ws + WS_BST_OFF);

    prep_kernel<<<NBLK_PREP, 128, 0, stream>>>(depth_logits, geom, pc, counts);
    ctxt_kernel<<<BN_TOT * 11, 256, 0, stream>>>(context, ctxT);
    scan_kernel<<<1, 1024, 0, stream>>>(counts, bstart);
    partition_kernel<<<NBLK_PREP, 256, 0, stream>>>(pc, counts, plist);
    solve_kernel<<<NBUCKET, 256, 0, stream>>>(bstart, plist, ctxT, out);
  } else {
    hipMemsetAsync(d_out, 0, (size_t)out_size * sizeof(float), stream);
    lift_scatter_kernel<<<BN_TOT * HWD, 256, 0, stream>>>(
        depth_logits, context, geom, out);
  }
}

// Round 13
// 131.158 us; speedup vs baseline: 1.9435x; 1.4815x over previous
//
#include <hip/hip_runtime.h>
#include <hip/hip_bf16.h>
#include <math.h>

// Problem constants (from reference)
#define BATCH 2
#define NCAM 6
#define BN_TOT (BATCH * NCAM)   // 12
#define DBINS 112
#define HH 16
#define WW 44
#define CCH 80
#define VXD 128
#define VYD 128
#define HWD (HH * WW)           // 704
#define NCELL (VXD * VYD)       // 16384
#define NCELL_TOT (BATCH * NCELL)      // 32768
#define NCOLS (BN_TOT * HWD)           // 8448 frustum columns
#define NPTS (NCOLS * DBINS)           // 946176 points
#define DCHUNK 28                      // 112 / 4

#define NBLK_PREP 264                  // 12 bn * 22 col-tiles of 32
#define PREP_PTS 3584                  // 32 cols * 112 bins
#define NBUCKET 1024                   // bucket = cell >> 5 (32 cells each)
#define FLATN (NBUCKET * NBLK_PREP)    // 270336
#define SOLVE_CAP 1280                 // >> max multinomial(~924+5sigma~1070)

// ---------------- workspace layout (bytes), all 16B-aligned ----------------
#define WS_CTXT_OFF    0u
#define WS_CTXT_BYTES  ((unsigned)NCOLS * CCH * 4u)            // 2,703,360
#define WS_PC_OFF      (WS_CTXT_OFF + WS_CTXT_BYTES)
#define WS_PC_BYTES    ((unsigned)NPTS * 8u)                   // 7,569,408
#define WS_PLIST_OFF   (WS_PC_OFF + WS_PC_BYTES)
#define WS_PLIST_BYTES ((unsigned)NPTS * 8u)                   // 7,569,408
#define WS_CNT_OFF     (WS_PLIST_OFF + WS_PLIST_BYTES)
#define WS_CNT_BYTES   ((unsigned)FLATN * 4u)                  // 1,081,344
#define WS_TOT_OFF     (WS_CNT_OFF + WS_CNT_BYTES)
#define WS_TOT_BYTES   ((unsigned)NBUCKET * 4u)                // 4,096
#define WS_BST_OFF     (WS_TOT_OFF + WS_TOT_BYTES)
#define WS_BST_BYTES   4128u                                   // 1025 ints + pad
#define WS_NEED        (WS_BST_OFF + WS_BST_BYTES)             // ~18.9 MB

// ============================================================
// K1 (prep): per 32-column tile; softmax over 112 bins (4x28 in
// regs), geom -> cell id, write pc[q]={cell,prob}, LDS 1024-bucket
// histogram -> counts[bucket][blk]. NO global atomics.
// ============================================================
__global__ __launch_bounds__(128) void prep_kernel(
    const float* __restrict__ depth_logits,  // (BN, D, HW)
    const int*   __restrict__ geom,          // (BN, D, HW, 3)
    int2* __restrict__ pc,                   // (D, COL) = {cell, prob_bits}
    int*  __restrict__ counts) {             // [1024][264]
  __shared__ float sred[4][32];
  __shared__ int shist[NBUCKET];
  const int t = threadIdx.x;
  for (int i = t; i < NBUCKET; i += 128) shist[i] = 0;

  const int col_l = t & 31;
  const int chunk = t >> 5;
  const int blk = blockIdx.x;              // 12 * 22
  const int bn = blk / 22;
  const int tile22 = blk - bn * 22;
  const int hw = tile22 * 32 + col_l;
  const int b = bn / NCAM;
  const int col = bn * HWD + hw;

  const float* lp =
      depth_logits + ((size_t)bn * DBINS + chunk * DCHUNK) * HWD + hw;
  float v[DCHUNK];
  float m = -INFINITY;
#pragma unroll
  for (int j = 0; j < DCHUNK; ++j) {
    v[j] = lp[(size_t)j * HWD];
    m = fmaxf(m, v[j]);
  }
  sred[chunk][col_l] = m;
  __syncthreads();
  m = fmaxf(fmaxf(sred[0][col_l], sred[1][col_l]),
            fmaxf(sred[2][col_l], sred[3][col_l]));
  float lsum = 0.0f;
#pragma unroll
  for (int j = 0; j < DCHUNK; ++j) {
    v[j] = __expf(v[j] - m);
    lsum += v[j];
  }
  __syncthreads();
  sred[chunk][col_l] = lsum;
  __syncthreads();
  const float inv = 1.0f / (sred[0][col_l] + sred[1][col_l] +
                            sred[2][col_l] + sred[3][col_l]);

  const int* gp = geom + (((size_t)bn * DBINS + chunk * DCHUNK) * HWD + hw) * 3;
#pragma unroll 4
  for (int j = 0; j < DCHUNK; ++j) {
    const int x = gp[(size_t)j * HWD * 3 + 0];
    const int y = gp[(size_t)j * HWD * 3 + 1];
    const int z = gp[(size_t)j * HWD * 3 + 2];
    int cell = -1;
    if (((unsigned)x < (unsigned)VXD) & ((unsigned)y < (unsigned)VYD) &
        ((unsigned)z < 128u)) {
      cell = (b << 14) + (y << 7) + x;
      atomicAdd(&shist[cell >> 5], 1);   // LDS
    }
    pc[(size_t)(chunk * DCHUNK + j) * NCOLS + col] =
        make_int2(cell, __float_as_int(v[j] * inv));
  }
  __syncthreads();
  for (int i = t; i < NBUCKET; i += 128) counts[i * NBLK_PREP + blk] = shist[i];
}

// ============================================================
// K2 (ctxT): context (BN,C,HW) -> ctxT (COL,C), LDS-tiled.
// ============================================================
__global__ __launch_bounds__(256) void ctxt_kernel(
    const float* __restrict__ context, float* __restrict__ ctxT) {
  __shared__ float tile[CCH][65];
  const int blk = blockIdx.x;              // 12 * 11
  const int bn = blk / 11;
  const int hw0 = (blk - bn * 11) * 64;
  const float* src = context + (size_t)bn * CCH * HWD + hw0;
  for (int p = threadIdx.x; p < CCH * 64; p += 256) {
    const int c = p >> 6;
    const int i = p & 63;
    tile[c][i] = src[(size_t)c * HWD + i];
  }
  __syncthreads();
  float* dst = ctxT + (size_t)(bn * HWD + hw0) * CCH;
  for (int p = threadIdx.x; p < CCH * 64; p += 256) {
    const int i = p / CCH;
    const int c = p - i * CCH;
    dst[p] = tile[c][i];
  }
}

// ============================================================
// K3a (scanA): one block per bucket; exclusive scan of its 264
// per-prep-block counts in place; bucket total out.
// ============================================================
__global__ __launch_bounds__(320) void scanA_kernel(
    int* __restrict__ counts, int* __restrict__ totals) {
  __shared__ int s[NBLK_PREP];
  const int t = threadIdx.x;
  const int k = blockIdx.x;                // bucket
  int orig = 0;
  if (t < NBLK_PREP) {
    orig = counts[k * NBLK_PREP + t];
    s[t] = orig;
  }
  __syncthreads();
  for (int d = 1; d < NBLK_PREP; d <<= 1) {
    int v = 0;
    if (t < NBLK_PREP && t >= d) v = s[t - d];
    __syncthreads();
    if (t < NBLK_PREP) s[t] += v;
    __syncthreads();
  }
  if (t < NBLK_PREP) counts[k * NBLK_PREP + t] = s[t] - orig;  // exclusive
  if (t == NBLK_PREP - 1) totals[k] = s[t];
}

// ============================================================
// K3b (scanB): 1 block; exclusive scan of 1024 bucket totals.
// ============================================================
__global__ __launch_bounds__(1024) void scanB_kernel(
    const int* __restrict__ totals, int* __restrict__ bucketStart) {
  __shared__ int wpart[16];
  const int t = threadIdx.x;
  const int lane = t & 63;
  const int wid = t >> 6;
  const int v = totals[t];
  int incl = v;
#pragma unroll
  for (int d = 1; d < 64; d <<= 1) {
    const int u = __shfl_up(incl, d, 64);
    if (lane >= d) incl += u;
  }
  if (lane == 63) wpart[wid] = incl;
  __syncthreads();
  if (t < 16) {
    const int w = wpart[t];
    int iw = w;
#pragma unroll
    for (int d = 1; d < 16; d <<= 1) {
      const int u = __shfl_up(iw, d, 16);
      if (t >= d) iw += u;
    }
    wpart[t] = iw - w;  // exclusive
  }
  __syncthreads();
  const int ex = wpart[wid] + incl - v;
  bucketStart[t] = ex;
  if (t == 1023) bucketStart[NBUCKET] = ex + v;
}

// ============================================================
// K4 (partition): mirror prep's grouping; in-LDS counting sort
// by bucket; flush contiguous runs at exact global offsets.
// Zero global atomics.
// ============================================================
__global__ __launch_bounds__(256) void partition_kernel(
    const int2* __restrict__ pc,
    const int*  __restrict__ offsets,    // [1024][264] local-exclusive
    const int*  __restrict__ bucketStart,
    int2* __restrict__ plist) {
  __shared__ int hist[NBUCKET], hoff[NBUCKET], hcur[NBUCKET], gdst[NBUCKET];
  __shared__ int2 stag[PREP_PTS];
  __shared__ int gaddr[PREP_PTS];
  __shared__ int wpart2[4];
  const int t = threadIdx.x;
  const int blk = blockIdx.x;            // 264, mirrors prep
  const int bn = blk / 22;
  const int tile22 = blk - bn * 22;
  const int colbase = bn * HWD + tile22 * 32;

  for (int i = t; i < NBUCKET; i += 256) hist[i] = 0;
  __syncthreads();

  int2 pay[14];
  int  bkt[14];
#pragma unroll
  for (int j = 0; j < 14; ++j) {
    const int p = t + j * 256;           // 0..3583
    const int d = p >> 5;
    const int col = colbase + (p & 31);
    const int2 pp = pc[(size_t)d * NCOLS + col];
    int bk = -1;
    if (pp.x >= 0) {
      bk = pp.x >> 5;
      atomicAdd(&hist[bk], 1);           // LDS
      pay[j] = make_int2(((pp.x & 31) << 14) | col, pp.y);
    }
    bkt[j] = bk;
  }
  __syncthreads();

  // scan 1024 bins with 256 threads (4 bins each)
  const int lane = t & 63, wid = t >> 6;
  const int h0 = hist[4 * t], h1 = hist[4 * t + 1];
  const int h2 = hist[4 * t + 2], h3 = hist[4 * t + 3];
  const int s4 = h0 + h1 + h2 + h3;
  int incl = s4;
#pragma unroll
  for (int d = 1; d < 64; d <<= 1) {
    const int u = __shfl_up(incl, d, 64);
    if (lane >= d) incl += u;
  }
  if (lane == 63) wpart2[wid] = incl;
  __syncthreads();
  int wbase = 0;
  if (wid == 1) wbase = wpart2[0];
  else if (wid == 2) wbase = wpart2[0] + wpart2[1];
  else if (wid == 3) wbase = wpart2[0] + wpart2[1] + wpart2[2];
  const int ex = wbase + incl - s4;
  hoff[4 * t] = ex;
  hoff[4 * t + 1] = ex + h0;
  hoff[4 * t + 2] = ex + h0 + h1;
  hoff[4 * t + 3] = ex + h0 + h1 + h2;
  hcur[4 * t] = 0; hcur[4 * t + 1] = 0; hcur[4 * t + 2] = 0; hcur[4 * t + 3] = 0;
#pragma unroll
  for (int i = 0; i < 4; ++i) {
    const int bb = 4 * t + i;
    gdst[bb] = bucketStart[bb] + offsets[bb * NBLK_PREP + blk];
  }
  __syncthreads();

  // scatter into staged (bucket-sorted) order
#pragma unroll
  for (int j = 0; j < 14; ++j) {
    if (bkt[j] >= 0) {
      const int r = atomicAdd(&hcur[bkt[j]], 1);   // LDS
      const int pos = hoff[bkt[j]] + r;
      stag[pos] = pay[j];
      gaddr[pos] = gdst[bkt[j]] + r;
    }
  }
  __syncthreads();

  const int nval = hoff[NBUCKET - 1] + hist[NBUCKET - 1];
  for (int i = t; i < nval; i += 256) {
    plist[gaddr[i]] = stag[i];           // coalesced runs per bucket
  }
}

// ============================================================
// K5 (solve): block per bucket (32 cells). Payloads to LDS,
// counting-sort by cell, wave-per-cell register gather (x4
// unrolled ctxT row loads), write final (b,c,y,x) directly.
// ============================================================
__global__ __launch_bounds__(256) void solve_kernel(
    const int*  __restrict__ bucketStart,
    const int2* __restrict__ plist,
    const float* __restrict__ ctxT,
    float* __restrict__ out) {
  __shared__ int2 spts[SOLVE_CAP];
  __shared__ float tile[32 * 81];
  __shared__ int hist[32], starts[33], cur[32];
  const int t = threadIdx.x;
  const int k = blockIdx.x;              // 1024
  const int b = k >> 9;
  const int y = (k & 511) >> 2;
  const int x0 = (k & 3) << 5;
  const int bs = bucketStart[k];
  const int be = bucketStart[k + 1];
  const int n_all = be - bs;
  const int n = min(n_all, SOLVE_CAP);

  if (t < 32) hist[t] = 0;
  __syncthreads();

  int2 rp[5];                            // 1280/256
  int nper = 0;
#pragma unroll
  for (int j = 0; j < 5; ++j) {
    const int i = t + j * 256;
    if (i < n) {
      const int2 p = plist[bs + i];
      rp[j] = p;
      atomicAdd(&hist[(p.x >> 14) & 31], 1);   // LDS
      nper = j + 1;
    }
  }
  __syncthreads();

  const int lane = t & 63, wid = t >> 6;
  if (t < 32) {
    const int h = hist[t];
    int incl = h;
#pragma unroll
    for (int d = 1; d < 32; d <<= 1) {
      const int u = __shfl_up(incl, d, 32);
      if (t >= d) incl += u;
    }
    starts[t] = incl - h;
    cur[t] = incl - h;
    if (t == 31) starts[32] = incl;
  }
  __syncthreads();

#pragma unroll
  for (int j = 0; j < 5; ++j) {
    if (j < nper) {
      const int key = (rp[j].x >> 14) & 31;
      const int r = atomicAdd(&cur[key], 1);   // LDS
      spts[r] = rp[j];
    }
  }
  __syncthreads();

  // wave handles 8 cells
  for (int ci = 0; ci < 8; ++ci) {
    const int xl = wid * 8 + ci;
    const int s0 = starts[xl];
    const int s1 = starts[xl + 1];
    float a0 = 0.0f, a1 = 0.0f;
    int i = s0;
    for (; i + 4 <= s1; i += 4) {
      const int2 p0 = spts[i], p1 = spts[i + 1], p2 = spts[i + 2], p3 = spts[i + 3];
      const float* c0 = ctxT + (size_t)(p0.x & 0x3FFF) * CCH;
      const float* c1 = ctxT + (size_t)(p1.x & 0x3FFF) * CCH;
      const float* c2 = ctxT + (size_t)(p2.x & 0x3FFF) * CCH;
      const float* c3 = ctxT + (size_t)(p3.x & 0x3FFF) * CCH;
      const float q0 = __int_as_float(p0.y), q1 = __int_as_float(p1.y);
      const float q2 = __int_as_float(p2.y), q3 = __int_as_float(p3.y);
      const float f0 = c0[lane], f1 = c1[lane], f2 = c2[lane], f3 = c3[lane];
      a0 = fmaf(q0, f0, a0);
      a0 = fmaf(q1, f1, a0);
      a0 = fmaf(q2, f2, a0);
      a0 = fmaf(q3, f3, a0);
      if (lane < CCH - 64) {
        a1 = fmaf(q0, c0[64 + lane], a1);
        a1 = fmaf(q1, c1[64 + lane], a1);
        a1 = fmaf(q2, c2[64 + lane], a1);
        a1 = fmaf(q3, c3[64 + lane], a1);
      }
    }
    for (; i < s1; ++i) {
      const int2 p = spts[i];
      const float pr = __int_as_float(p.y);
      const float* cb = ctxT + (size_t)(p.x & 0x3FFF) * CCH;
      a0 = fmaf(pr, cb[lane], a0);
      if (lane < CCH - 64) a1 = fmaf(pr, cb[64 + lane], a1);
    }
    tile[xl * 81 + lane] = a0;
    if (lane < CCH - 64) tile[xl * 81 + 64 + lane] = a1;
  }

  // overflow tail (statistically never taken; kept for correctness)
  for (int i = SOLVE_CAP; i < n_all; ++i) {
    const int2 p = plist[bs + i];
    const int key = (p.x >> 14) & 31;
    if ((key >> 3) == wid) {
      const float pr = __int_as_float(p.y);
      const float* cb = ctxT + (size_t)(p.x & 0x3FFF) * CCH;
      tile[key * 81 + lane] += pr * cb[lane];
      if (lane < CCH - 64) tile[key * 81 + 64 + lane] += pr * cb[64 + lane];
    }
  }
  __syncthreads();

  // write out[b][c][y][x0..x0+31], 128B rows
  float* dst = out + (((size_t)(b * CCH)) << 14) + (y << 7) + x0;
  for (int p = t; p < CCH * 32; p += 256) {
    const int c = p >> 5;
    const int xl = p & 31;
    dst[((size_t)c << 14) + xl] = tile[xl * 81 + c];
  }
}

// ============================================================
// Fallback: direct scatter-atomic (if ws too small).
// ============================================================
__global__ __launch_bounds__(256) void lift_scatter_kernel(
    const float* __restrict__ depth_logits, const float* __restrict__ context,
    const int* __restrict__ geom, float* __restrict__ accum) {
  __shared__ float sred[256];
  __shared__ float sprob[DBINS];
  __shared__ float sctx[CCH];
  __shared__ int   scell[DBINS];

  const int blk = blockIdx.x;
  const int bn  = blk / HWD;
  const int hw  = blk - bn * HWD;
  const int b   = bn / NCAM;
  const int t   = threadIdx.x;

  float v = -INFINITY;
  if (t < DBINS) v = depth_logits[(size_t)bn * DBINS * HWD + (size_t)t * HWD + hw];
  sred[t] = v;
  __syncthreads();
  for (int s = 128; s > 0; s >>= 1) {
    if (t < s) sred[t] = fmaxf(sred[t], sred[t + s]);
    __syncthreads();
  }
  const float m = sred[0];
  __syncthreads();
  float e = 0.0f;
  if (t < DBINS) e = __expf(v - m);
  sred[t] = e;
  __syncthreads();
  for (int s = 128; s > 0; s >>= 1) {
    if (t < s) sred[t] += sred[t + s];
    __syncthreads();
  }
  if (t < DBINS) sprob[t] = e / sred[0];
  if (t < CCH) sctx[t] = context[((size_t)bn * CCH + t) * HWD + hw];
  if (t < DBINS) {
    const size_t gbase = (((size_t)bn * DBINS + t) * HWD + hw) * 3;
    const int x = geom[gbase + 0];
    const int y = geom[gbase + 1];
    const int z = geom[gbase + 2];
    scell[t] = (x >= 0 && x < VXD && y >= 0 && y < VYD && z >= 0 && z < 128)
                   ? y * VXD + x : -1;
  }
  __syncthreads();

  float* __restrict__ base = accum + (((size_t)b * CCH) << 14);
  int d = t / CCH;
  int c = t - d * CCH;
#pragma unroll
  for (int k = 0; k < 35; ++k) {
    const int cell = scell[d];
    if (cell >= 0) {
      unsafeAtomicAdd(base + (((size_t)c) << 14) + cell, sprob[d] * sctx[c]);
    }
    d += 3; c += 16;
    if (c >= CCH) { c -= CCH; d += 1; }
  }
}

extern "C" void kernel_launch(void* const* d_in, const int* in_sizes, int n_in,
                              void* d_out, int out_size, void* d_ws, size_t ws_size,
                              hipStream_t stream) {
  const float* depth_logits = (const float*)d_in[0];
  const float* context      = (const float*)d_in[1];
  const int*   geom         = (const int*)d_in[2];
  float* out = (float*)d_out;
  char* ws = (char*)d_ws;

  if (ws_size >= WS_NEED) {
    float* ctxT   = (float*)(ws + WS_CTXT_OFF);
    int2*  pc     = (int2*)(ws + WS_PC_OFF);
    int2*  plist  = (int2*)(ws + WS_PLIST_OFF);
    int*   counts = (int*)(ws + WS_CNT_OFF);
    int*   totals = (int*)(ws + WS_TOT_OFF);
    int*   bstart = (int*)(ws + WS_BST_OFF);

    prep_kernel<<<NBLK_PREP, 128, 0, stream>>>(depth_logits, geom, pc, counts);
    ctxt_kernel<<<BN_TOT * 11, 256, 0, stream>>>(context, ctxT);
    scanA_kernel<<<NBUCKET, 320, 0, stream>>>(counts, totals);
    scanB_kernel<<<1, 1024, 0, stream>>>(totals, bstart);
    partition_kernel<<<NBLK_PREP, 256, 0, stream>>>(pc, counts, bstart, plist);
    solve_kernel<<<NBUCKET, 256, 0, stream>>>(bstart, plist, ctxT, out);
  } else {
    hipMemsetAsync(d_out, 0, (size_t)out_size * sizeof(float), stream);
    lift_scatter_kernel<<<BN_TOT * HWD, 256, 0, stream>>>(
        depth_logits, context, geom, out);
  }
}

// Round 15
// 123.410 us; speedup vs baseline: 2.0656x; 1.0628x over previous
//
#include <hip/hip_runtime.h>
#include <hip/hip_bf16.h>
#include <math.h>

// Problem constants (from reference)
#define BATCH 2
#define NCAM 6
#define BN_TOT (BATCH * NCAM)   // 12
#define DBINS 112
#define HH 16
#define WW 44
#define CCH 80
#define VXD 128
#define VYD 128
#define HWD (HH * WW)           // 704
#define NCELL (VXD * VYD)       // 16384
#define NCELL_TOT (BATCH * NCELL)      // 32768
#define NCOLS (BN_TOT * HWD)           // 8448 frustum columns
#define NPTS (NCOLS * DBINS)           // 946176 points
#define DCHUNK 28                      // 112 / 4

#define NBLK_PREP 264                  // 12 bn * 22 col-tiles of 32
#define PREP_PTS 3584                  // 32 cols * 112 bins
#define NBUCKET 1024                   // bucket = cell >> 5 (32 cells each)
#define FLATN (NBUCKET * NBLK_PREP)    // 270336
#define SOLVE_CAP 1280                 // >> max multinomial(~924+5sigma~1070)

// ---------------- workspace layout (bytes), all 16B-aligned ----------------
#define WS_CTXT_OFF    0u
#define WS_CTXT_BYTES  ((unsigned)NCOLS * CCH * 4u)            // 2,703,360
#define WS_PC_OFF      (WS_CTXT_OFF + WS_CTXT_BYTES)
#define WS_PC_BYTES    ((unsigned)NPTS * 8u)                   // 7,569,408
#define WS_PLIST_OFF   (WS_PC_OFF + WS_PC_BYTES)
#define WS_PLIST_BYTES ((unsigned)NPTS * 8u)                   // 7,569,408
#define WS_CNT_OFF     (WS_PLIST_OFF + WS_PLIST_BYTES)
#define WS_CNT_BYTES   ((unsigned)FLATN * 4u)                  // 1,081,344
#define WS_TOT_OFF     (WS_CNT_OFF + WS_CNT_BYTES)
#define WS_TOT_BYTES   ((unsigned)NBUCKET * 4u)                // 4,096
#define WS_BST_OFF     (WS_TOT_OFF + WS_TOT_BYTES)
#define WS_BST_BYTES   4128u                                   // 1025 ints + pad
#define WS_NEED        (WS_BST_OFF + WS_BST_BYTES)             // ~18.9 MB

// ============================================================
// K1 (prep): per 32-column tile; softmax over 112 bins (4x28 in
// regs), geom -> cell id, pc[q]={cell,prob}, 1024-bucket LDS
// histogram -> counts[bucket][blk], AND fused context transpose
// (BN,C,HW)->(COL,C) via LDS tile. NO global atomics.
// ============================================================
__global__ __launch_bounds__(128) void prep_kernel(
    const float* __restrict__ depth_logits,  // (BN, D, HW)
    const float* __restrict__ context,       // (BN, C, HW)
    const int*   __restrict__ geom,          // (BN, D, HW, 3)
    int2*  __restrict__ pc,                  // (D, COL) = {cell, prob_bits}
    float* __restrict__ ctxT,                // (COL, C)
    int*   __restrict__ counts) {            // [1024][264]
  __shared__ float sred[4][32];
  __shared__ int shist[NBUCKET];
  __shared__ float ctile[32][CCH + 1];
  const int t = threadIdx.x;
  for (int i = t; i < NBUCKET; i += 128) shist[i] = 0;

  const int col_l = t & 31;
  const int chunk = t >> 5;
  const int blk = blockIdx.x;              // 12 * 22
  const int bn = blk / 22;
  const int tile22 = blk - bn * 22;
  const int hw0 = tile22 * 32;
  const int hw = hw0 + col_l;
  const int b = bn / NCAM;
  const int col = bn * HWD + hw;

  // ---- fused ctx transpose: stage (c, i2) -> ctile[i2][c] ----
  const float* csrc = context + (size_t)bn * CCH * HWD + hw0;
  for (int p = t; p < 32 * CCH; p += 128) {
    const int c = p >> 5;
    const int i2 = p & 31;
    ctile[i2][c] = csrc[(size_t)c * HWD + i2];
  }

  // ---- softmax over depth bins ----
  const float* lp =
      depth_logits + ((size_t)bn * DBINS + chunk * DCHUNK) * HWD + hw;
  float v[DCHUNK];
  float m = -INFINITY;
#pragma unroll
  for (int j = 0; j < DCHUNK; ++j) {
    v[j] = lp[(size_t)j * HWD];
    m = fmaxf(m, v[j]);
  }
  sred[chunk][col_l] = m;
  __syncthreads();
  m = fmaxf(fmaxf(sred[0][col_l], sred[1][col_l]),
            fmaxf(sred[2][col_l], sred[3][col_l]));
  float lsum = 0.0f;
#pragma unroll
  for (int j = 0; j < DCHUNK; ++j) {
    v[j] = __expf(v[j] - m);
    lsum += v[j];
  }
  __syncthreads();
  sred[chunk][col_l] = lsum;
  __syncthreads();
  const float inv = 1.0f / (sred[0][col_l] + sred[1][col_l] +
                            sred[2][col_l] + sred[3][col_l]);

  const int* gp = geom + (((size_t)bn * DBINS + chunk * DCHUNK) * HWD + hw) * 3;
#pragma unroll 4
  for (int j = 0; j < DCHUNK; ++j) {
    const int x = gp[(size_t)j * HWD * 3 + 0];
    const int y = gp[(size_t)j * HWD * 3 + 1];
    const int z = gp[(size_t)j * HWD * 3 + 2];
    int cell = -1;
    if (((unsigned)x < (unsigned)VXD) & ((unsigned)y < (unsigned)VYD) &
        ((unsigned)z < 128u)) {
      cell = (b << 14) + (y << 7) + x;
      atomicAdd(&shist[cell >> 5], 1);   // LDS
    }
    pc[(size_t)(chunk * DCHUNK + j) * NCOLS + col] =
        make_int2(cell, __float_as_int(v[j] * inv));
  }
  __syncthreads();
  for (int i = t; i < NBUCKET; i += 128) counts[i * NBLK_PREP + blk] = shist[i];

  // ---- flush ctx tile: (COL, C) rows, coalesced 320B runs ----
  float* cdst = ctxT + (size_t)(bn * HWD + hw0) * CCH;
  for (int p = t; p < 32 * CCH; p += 128) {
    const int i2 = p / CCH;
    const int c = p - i2 * CCH;
    cdst[p] = ctile[i2][c];
  }
}

// ============================================================
// K2 (scanA): one block per bucket; exclusive scan of its 264
// per-prep-block counts in place; bucket total out.
// ============================================================
__global__ __launch_bounds__(320) void scanA_kernel(
    int* __restrict__ counts, int* __restrict__ totals) {
  __shared__ int s[NBLK_PREP];
  const int t = threadIdx.x;
  const int k = blockIdx.x;                // bucket
  int orig = 0;
  if (t < NBLK_PREP) {
    orig = counts[k * NBLK_PREP + t];
    s[t] = orig;
  }
  __syncthreads();
  for (int d = 1; d < NBLK_PREP; d <<= 1) {
    int v = 0;
    if (t < NBLK_PREP && t >= d) v = s[t - d];
    __syncthreads();
    if (t < NBLK_PREP) s[t] += v;
    __syncthreads();
  }
  if (t < NBLK_PREP) counts[k * NBLK_PREP + t] = s[t] - orig;  // exclusive
  if (t == NBLK_PREP - 1) totals[k] = s[t];
}

// ============================================================
// K3 (partition): mirror prep's grouping; in-LDS counting sort
// by bucket; flush contiguous runs at exact global offsets.
// Also block-scans totals[] -> bucket bases (replacing scanB);
// block 0 publishes bucketStart[] for solve. Zero global atomics.
// ============================================================
__global__ __launch_bounds__(256) void partition_kernel(
    const int2* __restrict__ pc,
    const int*  __restrict__ offsets,    // [1024][264] local-exclusive
    const int*  __restrict__ totals,     // [1024]
    int*  __restrict__ bucketStart,      // [1025], written by blk 0
    int2* __restrict__ plist) {
  __shared__ int hist[NBUCKET], hoff[NBUCKET], hcur[NBUCKET], gdst[NBUCKET];
  __shared__ int2 stag[PREP_PTS];
  __shared__ int gaddr[PREP_PTS];
  __shared__ int wpartA[4], wpartB[4];
  const int t = threadIdx.x;
  const int blk = blockIdx.x;            // 264, mirrors prep
  const int bn = blk / 22;
  const int tile22 = blk - bn * 22;
  const int colbase = bn * HWD + tile22 * 32;

  for (int i = t; i < NBUCKET; i += 256) hist[i] = 0;
  __syncthreads();

  int2 pay[14];
  int  bkt[14];
#pragma unroll
  for (int j = 0; j < 14; ++j) {
    const int p = t + j * 256;           // 0..3583
    const int d = p >> 5;
    const int col = colbase + (p & 31);
    const int2 pp = pc[(size_t)d * NCOLS + col];
    int bk = -1;
    if (pp.x >= 0) {
      bk = pp.x >> 5;
      atomicAdd(&hist[bk], 1);           // LDS
      pay[j] = make_int2(((pp.x & 31) << 14) | col, pp.y);
    }
    bkt[j] = bk;
  }
  __syncthreads();

  const int lane = t & 63, wid = t >> 6;

  // ---- scan A: local hist (1024 bins, 4/thread) -> hoff ----
  const int h0 = hist[4 * t], h1 = hist[4 * t + 1];
  const int h2 = hist[4 * t + 2], h3 = hist[4 * t + 3];
  const int s4 = h0 + h1 + h2 + h3;
  int inclA = s4;
#pragma unroll
  for (int d = 1; d < 64; d <<= 1) {
    const int u = __shfl_up(inclA, d, 64);
    if (lane >= d) inclA += u;
  }
  if (lane == 63) wpartA[wid] = inclA;

  // ---- scan B inputs: bucket totals (independent loads) ----
  const int u0 = totals[4 * t], u1 = totals[4 * t + 1];
  const int u2 = totals[4 * t + 2], u3 = totals[4 * t + 3];
  const int su = u0 + u1 + u2 + u3;
  __syncthreads();

  int wbaseA = 0;
  if (wid == 1) wbaseA = wpartA[0];
  else if (wid == 2) wbaseA = wpartA[0] + wpartA[1];
  else if (wid == 3) wbaseA = wpartA[0] + wpartA[1] + wpartA[2];
  const int exA = wbaseA + inclA - s4;
  hoff[4 * t] = exA;
  hoff[4 * t + 1] = exA + h0;
  hoff[4 * t + 2] = exA + h0 + h1;
  hoff[4 * t + 3] = exA + h0 + h1 + h2;
  hcur[4 * t] = 0; hcur[4 * t + 1] = 0; hcur[4 * t + 2] = 0; hcur[4 * t + 3] = 0;

  int inclB = su;
#pragma unroll
  for (int d = 1; d < 64; d <<= 1) {
    const int u = __shfl_up(inclB, d, 64);
    if (lane >= d) inclB += u;
  }
  if (lane == 63) wpartB[wid] = inclB;
  __syncthreads();

  int wbaseB = 0;
  if (wid == 1) wbaseB = wpartB[0];
  else if (wid == 2) wbaseB = wpartB[0] + wpartB[1];
  else if (wid == 3) wbaseB = wpartB[0] + wpartB[1] + wpartB[2];
  const int exB = wbaseB + inclB - su;
  const int bv0 = exB, bv1 = exB + u0, bv2 = exB + u0 + u1,
            bv3 = exB + u0 + u1 + u2;
  gdst[4 * t]     = bv0 + offsets[(4 * t)     * NBLK_PREP + blk];
  gdst[4 * t + 1] = bv1 + offsets[(4 * t + 1) * NBLK_PREP + blk];
  gdst[4 * t + 2] = bv2 + offsets[(4 * t + 2) * NBLK_PREP + blk];
  gdst[4 * t + 3] = bv3 + offsets[(4 * t + 3) * NBLK_PREP + blk];
  if (blk == 0) {
    bucketStart[4 * t] = bv0;
    bucketStart[4 * t + 1] = bv1;
    bucketStart[4 * t + 2] = bv2;
    bucketStart[4 * t + 3] = bv3;
    if (t == 255) bucketStart[NBUCKET] = bv3 + u3;
  }
  __syncthreads();

  // scatter into staged (bucket-sorted) order
#pragma unroll
  for (int j = 0; j < 14; ++j) {
    if (bkt[j] >= 0) {
      const int r = atomicAdd(&hcur[bkt[j]], 1);   // LDS
      const int pos = hoff[bkt[j]] + r;
      stag[pos] = pay[j];
      gaddr[pos] = gdst[bkt[j]] + r;
    }
  }
  __syncthreads();

  const int nval = hoff[NBUCKET - 1] + hist[NBUCKET - 1];
  for (int i = t; i < nval; i += 256) {
    plist[gaddr[i]] = stag[i];           // coalesced runs per bucket
  }
}

// ============================================================
// K4 (solve): 2 blocks per bucket (x-halves of 16 cells each)
// for occupancy. Filter bucket segment by half, LDS counting-
// sort by cell, wave-per-cell register gather (x4 unrolled),
// write final (b,c,y,x) directly. Covers every output element.
// ============================================================
__global__ __launch_bounds__(256) void solve_kernel(
    const int*  __restrict__ bucketStart,
    const int2* __restrict__ plist,
    const float* __restrict__ ctxT,
    float* __restrict__ out) {
  __shared__ int2 spts[SOLVE_CAP];
  __shared__ float tile[16 * 81];
  __shared__ int hist[16], starts[17], cur[16];
  const int t = threadIdx.x;
  const int kb = blockIdx.x >> 1;        // bucket 0..1023
  const int half = blockIdx.x & 1;       // x-half: cells [half*16, half*16+16)
  const int b = kb >> 9;
  const int y = (kb & 511) >> 2;
  const int x0 = ((kb & 3) << 5) + (half << 4);
  const int bs = bucketStart[kb];
  const int be = bucketStart[kb + 1];
  const int n_all = be - bs;
  const int n = min(n_all, SOLVE_CAP);

  if (t < 16) hist[t] = 0;
  __syncthreads();

  int2 rp[5];                            // 1280/256
  int  rk[5];                            // local cell key, -1 = not ours
#pragma unroll
  for (int j = 0; j < 5; ++j) {
    rk[j] = -1;
    const int i = t + j * 256;
    if (i < n) {
      const int2 p = plist[bs + i];
      const int key = (p.x >> 14) & 31;
      if ((key >> 4) == half) {
        rp[j] = p;
        rk[j] = key & 15;
        atomicAdd(&hist[key & 15], 1);   // LDS
      }
    }
  }
  __syncthreads();

  const int lane = t & 63, wid = t >> 6;
  if (t < 16) {
    const int h = hist[t];
    int incl = h;
#pragma unroll
    for (int d = 1; d < 16; d <<= 1) {
      const int u = __shfl_up(incl, d, 16);
      if (t >= d) incl += u;
    }
    starts[t] = incl - h;
    cur[t] = incl - h;
    if (t == 15) starts[16] = incl;
  }
  __syncthreads();

#pragma unroll
  for (int j = 0; j < 5; ++j) {
    if (rk[j] >= 0) {
      const int r = atomicAdd(&cur[rk[j]], 1);   // LDS
      spts[r] = rp[j];
    }
  }
  __syncthreads();

  // wave handles 4 cells
  for (int ci = 0; ci < 4; ++ci) {
    const int xl = wid * 4 + ci;         // 0..15
    const int s0 = starts[xl];
    const int s1 = starts[xl + 1];
    float a0 = 0.0f, a1 = 0.0f;
    int i = s0;
    for (; i + 4 <= s1; i += 4) {
      const int2 p0 = spts[i], p1 = spts[i + 1], p2 = spts[i + 2], p3 = spts[i + 3];
      const float* c0 = ctxT + (size_t)(p0.x & 0x3FFF) * CCH;
      const float* c1 = ctxT + (size_t)(p1.x & 0x3FFF) * CCH;
      const float* c2 = ctxT + (size_t)(p2.x & 0x3FFF) * CCH;
      const float* c3 = ctxT + (size_t)(p3.x & 0x3FFF) * CCH;
      const float q0 = __int_as_float(p0.y), q1 = __int_as_float(p1.y);
      const float q2 = __int_as_float(p2.y), q3 = __int_as_float(p3.y);
      const float f0 = c0[lane], f1 = c1[lane], f2 = c2[lane], f3 = c3[lane];
      a0 = fmaf(q0, f0, a0);
      a0 = fmaf(q1, f1, a0);
      a0 = fmaf(q2, f2, a0);
      a0 = fmaf(q3, f3, a0);
      if (lane < CCH - 64) {
        a1 = fmaf(q0, c0[64 + lane], a1);
        a1 = fmaf(q1, c1[64 + lane], a1);
        a1 = fmaf(q2, c2[64 + lane], a1);
        a1 = fmaf(q3, c3[64 + lane], a1);
      }
    }
    for (; i < s1; ++i) {
      const int2 p = spts[i];
      const float pr = __int_as_float(p.y);
      const float* cb = ctxT + (size_t)(p.x & 0x3FFF) * CCH;
      a0 = fmaf(pr, cb[lane], a0);
      if (lane < CCH - 64) a1 = fmaf(pr, cb[64 + lane], a1);
    }
    tile[xl * 81 + lane] = a0;
    if (lane < CCH - 64) tile[xl * 81 + 64 + lane] = a1;
  }

  // overflow tail (statistically never taken; kept for correctness)
  for (int i = SOLVE_CAP; i < n_all; ++i) {
    const int2 p = plist[bs + i];
    const int key = (p.x >> 14) & 31;
    if ((key >> 4) == half && (((key & 15) >> 2) == wid)) {
      const float pr = __int_as_float(p.y);
      const float* cb = ctxT + (size_t)(p.x & 0x3FFF) * CCH;
      tile[(key & 15) * 81 + lane] += pr * cb[lane];
      if (lane < CCH - 64) tile[(key & 15) * 81 + 64 + lane] += pr * cb[64 + lane];
    }
  }
  __syncthreads();

  // write out[b][c][y][x0..x0+15]
  float* dst = out + (((size_t)(b * CCH)) << 14) + (y << 7) + x0;
  for (int p = t; p < CCH * 16; p += 256) {
    const int c = p >> 4;
    const int xl = p & 15;
    dst[((size_t)c << 14) + xl] = tile[xl * 81 + c];
  }
}

// ============================================================
// Fallback: direct scatter-atomic (if ws too small).
// ============================================================
__global__ __launch_bounds__(256) void lift_scatter_kernel(
    const float* __restrict__ depth_logits, const float* __restrict__ context,
    const int* __restrict__ geom, float* __restrict__ accum) {
  __shared__ float sred[256];
  __shared__ float sprob[DBINS];
  __shared__ float sctx[CCH];
  __shared__ int   scell[DBINS];

  const int blk = blockIdx.x;
  const int bn  = blk / HWD;
  const int hw  = blk - bn * HWD;
  const int b   = bn / NCAM;
  const int t   = threadIdx.x;

  float v = -INFINITY;
  if (t < DBINS) v = depth_logits[(size_t)bn * DBINS * HWD + (size_t)t * HWD + hw];
  sred[t] = v;
  __syncthreads();
  for (int s = 128; s > 0; s >>= 1) {
    if (t < s) sred[t] = fmaxf(sred[t], sred[t + s]);
    __syncthreads();
  }
  const float m = sred[0];
  __syncthreads();
  float e = 0.0f;
  if (t < DBINS) e = __expf(v - m);
  sred[t] = e;
  __syncthreads();
  for (int s = 128; s > 0; s >>= 1) {
    if (t < s) sred[t] += sred[t + s];
    __syncthreads();
  }
  if (t < DBINS) sprob[t] = e / sred[0];
  if (t < CCH) sctx[t] = context[((size_t)bn * CCH + t) * HWD + hw];
  if (t < DBINS) {
    const size_t gbase = (((size_t)bn * DBINS + t) * HWD + hw) * 3;
    const int x = geom[gbase + 0];
    const int y = geom[gbase + 1];
    const int z = geom[gbase + 2];
    scell[t] = (x >= 0 && x < VXD && y >= 0 && y < VYD && z >= 0 && z < 128)
                   ? y * VXD + x : -1;
  }
  __syncthreads();

  float* __restrict__ base = accum + (((size_t)b * CCH) << 14);
  int d = t / CCH;
  int c = t - d * CCH;
#pragma unroll
  for (int k = 0; k < 35; ++k) {
    const int cell = scell[d];
    if (cell >= 0) {
      unsafeAtomicAdd(base + (((size_t)c) << 14) + cell, sprob[d] * sctx[c]);
    }
    d += 3; c += 16;
    if (c >= CCH) { c -= CCH; d += 1; }
  }
}

extern "C" void kernel_launch(void* const* d_in, const int* in_sizes, int n_in,
                              void* d_out, int out_size, void* d_ws, size_t ws_size,
                              hipStream_t stream) {
  const float* depth_logits = (const float*)d_in[0];
  const float* context      = (const float*)d_in[1];
  const int*   geom         = (const int*)d_in[2];
  float* out = (float*)d_out;
  char* ws = (char*)d_ws;

  if (ws_size >= WS_NEED) {
    float* ctxT   = (float*)(ws + WS_CTXT_OFF);
    int2*  pc     = (int2*)(ws + WS_PC_OFF);
    int2*  plist  = (int2*)(ws + WS_PLIST_OFF);
    int*   counts = (int*)(ws + WS_CNT_OFF);
    int*   totals = (int*)(ws + WS_TOT_OFF);
    int*   bstart = (int*)(ws + WS_BST_OFF);

    prep_kernel<<<NBLK_PREP, 128, 0, stream>>>(depth_logits, context, geom,
                                               pc, ctxT, counts);
    scanA_kernel<<<NBUCKET, 320, 0, stream>>>(counts, totals);
    partition_kernel<<<NBLK_PREP, 256, 0, stream>>>(pc, counts, totals,
                                                    bstart, plist);
    solve_kernel<<<NBUCKET * 2, 256, 0, stream>>>(bstart, plist, ctxT, out);
  } else {
    hipMemsetAsync(d_out, 0, (size_t)out_size * sizeof(float), stream);
    lift_scatter_kernel<<<BN_TOT * HWD, 256, 0, stream>>>(
        depth_logits, context, geom, out);
  }
}